// Round 1
// baseline (277.403 us; speedup 1.0000x reference)
//
#include <hip/hip_runtime.h>

#define T_STEPS 200
#define IN_DIM 1086

using f32x4v = __attribute__((ext_vector_type(4))) float;
using bf16x8 = __attribute__((ext_vector_type(8))) short;
using u32x4  = __attribute__((ext_vector_type(4))) unsigned int;

__device__ __forceinline__ float rl_f(float v, int lane) {
    return __uint_as_float((unsigned)__builtin_amdgcn_readlane((int)__float_as_uint(v), lane));
}

// sigmoid(x) = 1/(1+exp(-x)); exp via v_exp_f32, recip via v_rcp_f32. Inf-safe both ends.
__device__ __forceinline__ float sigm(float x) {
    float e = exp2f(-1.4426950408889634f * x);
    return __builtin_amdgcn_rcpf(1.0f + e);
}
// tanh(x) = 2*sigmoid(2x) - 1. Inf-safe both ends.
__device__ __forceinline__ float tanh_fast(float x) {
    float e = exp2f(-2.8853900817779268f * x);
    float s = __builtin_amdgcn_rcpf(1.0f + e);
    return fmaf(2.0f, s, -1.0f);
}

// ---------------------------------------------------------------------------
// pre0 = x @ W_ih0^T + b0   (51200x1086)*(1086x64) -> (51200,64) fp32
// hi/lo bf16 split, 3 MFMA passes per tile => ~2^-15 relative accuracy.
// Tile: BM=128 (4 waves x 32 rows), BN=64 (all), BK=32.
// LDS layout [kgroup(4)][row][8 ushort] -> frag reads & staging writes conflict-free.
// ---------------------------------------------------------------------------
__global__ __launch_bounds__(256) void pre0_gemm(
    const float* __restrict__ X, const float* __restrict__ W,
    const float* __restrict__ bias, float* __restrict__ out)
{
    __shared__ unsigned short AhL[4][128][8];
    __shared__ unsigned short AlL[4][128][8];
    __shared__ unsigned short BhL[4][64][8];
    __shared__ unsigned short BlL[4][64][8];

    const int tid  = threadIdx.x;
    const int lane = tid & 63;
    const int wv   = tid >> 6;           // wave 0..3
    const long m0  = (long)blockIdx.x * 128;

    const int sr  = tid >> 1;            // staging row 0..127
    const int skb = (tid & 1) * 16;      // k base within 32-tile
    const int wr  = sr & 63;             // W staging row (tid<128 only)
    const float* xsrc = X + (m0 + sr) * (long)IN_DIM + skb;
    const float* wsrc = W + (long)wr * IN_DIM + skb;

    const int fr = lane & 15;            // frag row/col
    const int kg = lane >> 4;            // k-group 0..3

    f32x4v acc[2][4];
    #pragma unroll
    for (int mf = 0; mf < 2; ++mf)
        #pragma unroll
        for (int nf = 0; nf < 4; ++nf)
            #pragma unroll
            for (int r = 0; r < 4; ++r) acc[mf][nf][r] = 0.0f;

    for (int k0 = 0; k0 < IN_DIM; k0 += 32) {
        // ---- global loads (16 floats each; X all threads, W for tid<128)
        float xv[16];
        #pragma unroll
        for (int j = 0; j < 16; j += 2) {
            int k = k0 + skb + j;
            if (k + 2 <= IN_DIM) {
                float2 t = *(const float2*)(xsrc + k0 + j);   // 8B aligned (all terms even)
                xv[j] = t.x; xv[j + 1] = t.y;
            } else { xv[j] = 0.0f; xv[j + 1] = 0.0f; }        // k even & >= IN_DIM
        }
        float wvv[16];
        if (tid < 128) {
            #pragma unroll
            for (int j = 0; j < 16; j += 2) {
                int k = k0 + skb + j;
                if (k + 2 <= IN_DIM) {
                    float2 t = *(const float2*)(wsrc + k0 + j);
                    wvv[j] = t.x; wvv[j + 1] = t.y;
                } else { wvv[j] = 0.0f; wvv[j + 1] = 0.0f; }
            }
        }
        __syncthreads();   // previous tile's frag reads done

        // ---- convert to hi/lo bf16 (truncation; lo = exact residual) & store
        #pragma unroll
        for (int q = 0; q < 2; ++q) {
            u32x4 hw, lw;
            #pragma unroll
            for (int p = 0; p < 4; ++p) {
                float a0 = xv[q * 8 + 2 * p], a1 = xv[q * 8 + 2 * p + 1];
                unsigned u0 = __float_as_uint(a0), u1 = __float_as_uint(a1);
                unsigned h0 = u0 & 0xffff0000u, h1 = u1 & 0xffff0000u;
                hw[p] = (u0 >> 16) | h1;
                float l0 = a0 - __uint_as_float(h0);
                float l1 = a1 - __uint_as_float(h1);
                lw[p] = (__float_as_uint(l0) >> 16) | (__float_as_uint(l1) & 0xffff0000u);
            }
            int kgs = (tid & 1) * 2 + q;
            *(u32x4*)&AhL[kgs][sr][0] = hw;
            *(u32x4*)&AlL[kgs][sr][0] = lw;
        }
        if (tid < 128) {
            #pragma unroll
            for (int q = 0; q < 2; ++q) {
                u32x4 hw, lw;
                #pragma unroll
                for (int p = 0; p < 4; ++p) {
                    float a0 = wvv[q * 8 + 2 * p], a1 = wvv[q * 8 + 2 * p + 1];
                    unsigned u0 = __float_as_uint(a0), u1 = __float_as_uint(a1);
                    unsigned h0 = u0 & 0xffff0000u, h1 = u1 & 0xffff0000u;
                    hw[p] = (u0 >> 16) | h1;
                    float l0 = a0 - __uint_as_float(h0);
                    float l1 = a1 - __uint_as_float(h1);
                    lw[p] = (__float_as_uint(l0) >> 16) | (__float_as_uint(l1) & 0xffff0000u);
                }
                int kgs = (tid & 1) * 2 + q;
                *(u32x4*)&BhL[kgs][wr][0] = hw;
                *(u32x4*)&BlL[kgs][wr][0] = lw;
            }
        }
        __syncthreads();

        // ---- fragments + MFMA (A rows of X, B rows of W == columns of W^T)
        bf16x8 ah[2], al[2], bh[4], bl[4];
        #pragma unroll
        for (int mf = 0; mf < 2; ++mf) {
            ah[mf] = *(const bf16x8*)&AhL[kg][wv * 32 + mf * 16 + fr][0];
            al[mf] = *(const bf16x8*)&AlL[kg][wv * 32 + mf * 16 + fr][0];
        }
        #pragma unroll
        for (int nf = 0; nf < 4; ++nf) {
            bh[nf] = *(const bf16x8*)&BhL[kg][nf * 16 + fr][0];
            bl[nf] = *(const bf16x8*)&BlL[kg][nf * 16 + fr][0];
        }
        #pragma unroll
        for (int mf = 0; mf < 2; ++mf)
            #pragma unroll
            for (int nf = 0; nf < 4; ++nf) {
                acc[mf][nf] = __builtin_amdgcn_mfma_f32_16x16x32_bf16(ah[mf], bh[nf], acc[mf][nf], 0, 0, 0);
                acc[mf][nf] = __builtin_amdgcn_mfma_f32_16x16x32_bf16(al[mf], bh[nf], acc[mf][nf], 0, 0, 0);
                acc[mf][nf] = __builtin_amdgcn_mfma_f32_16x16x32_bf16(ah[mf], bl[nf], acc[mf][nf], 0, 0, 0);
            }
    }

    // ---- epilogue: +bias, store fp32. C/D map: col=lane&15, row=(lane>>4)*4+r
    float bvv[4];
    #pragma unroll
    for (int nf = 0; nf < 4; ++nf) bvv[nf] = bias[nf * 16 + fr];
    #pragma unroll
    for (int mf = 0; mf < 2; ++mf)
        #pragma unroll
        for (int nf = 0; nf < 4; ++nf)
            #pragma unroll
            for (int r = 0; r < 4; ++r) {
                long row = m0 + wv * 32 + mf * 16 + kg * 4 + r;
                out[row * 64 + nf * 16 + fr] = acc[mf][nf][r] + bvv[nf];
            }
}

// ---------------------------------------------------------------------------
// Scan: one wave per batch element. Lane g owns gate g (i:0-15 f:16-31 g:32-47 o:48-63).
// h replicated to all lanes as uniform (readlane -> SGPR). c kept per-lane for j=g&15.
// ---------------------------------------------------------------------------
__device__ __forceinline__ void lstm_step_tail(
    float acc, float& c, const int j, const bool isg,
    float h[16], float* out_lds, int t, const int g, const bool store)
{
    float xx = isg ? (acc + acc) : acc;
    float e  = exp2f(-1.4426950408889634f * xx);
    float s  = __builtin_amdgcn_rcpf(1.0f + e);
    float a  = isg ? fmaf(2.0f, s, -1.0f) : s;   // tanh for g-gate, sigmoid else
    float iv = __shfl(a, j, 64);
    float fv = __shfl(a, j + 16, 64);
    float gv = __shfl(a, j + 32, 64);
    float ov = __shfl(a, j + 48, 64);
    c = fmaf(fv, c, iv * gv);
    float th = tanh_fast(c);
    float hn = ov * th;
    if (store && g < 16) out_lds[t * 16 + g] = hn;
    #pragma unroll
    for (int k = 0; k < 16; ++k) h[k] = rl_f(hn, k);
}

// layer 0a: pre-activations from global (bias already folded in by GEMM)
__device__ __forceinline__ void scan_pre_layer(
    const float* __restrict__ pre, float* out_lds,
    const float* __restrict__ w_hh, const int g, float h[16])
{
    float whh[16];
    #pragma unroll
    for (int k = 0; k < 16; ++k) whh[k] = w_hh[g * 16 + k];
    #pragma unroll
    for (int k = 0; k < 16; ++k) h[k] = 0.0f;
    float c = 0.0f;
    const int j = g & 15;
    const bool isg = (g >= 32) && (g < 48);
    const float* pb = pre + g;
    float pv = pb[0];
    for (int t = 0; t < T_STEPS; ++t) {
        float pn = (t + 1 < T_STEPS) ? pb[(t + 1) * 64] : 0.0f;  // prefetch off-chain
        float s0 = fmaf(whh[0], h[0], pv);
        float s1 = whh[1] * h[1];
        float s2 = whh[2] * h[2];
        float s3 = whh[3] * h[3];
        #pragma unroll
        for (int k = 4; k < 16; k += 4) {
            s0 = fmaf(whh[k + 0], h[k + 0], s0);
            s1 = fmaf(whh[k + 1], h[k + 1], s1);
            s2 = fmaf(whh[k + 2], h[k + 2], s2);
            s3 = fmaf(whh[k + 3], h[k + 3], s3);
        }
        float acc = (s0 + s1) + (s2 + s3);
        lstm_step_tail(acc, c, j, isg, h, out_lds, t, g, true);
        pv = pn;
    }
}

// layers 0b/1a/1b: input sequence from LDS, w_ih fused
template<bool STORE>
__device__ __forceinline__ void scan_lds_layer(
    const float* in_lds, float* out_lds,
    const float* __restrict__ w_ih, const float* __restrict__ w_hh,
    const float* __restrict__ bias, const int g, float h[16])
{
    float wih[16], whh[16];
    #pragma unroll
    for (int k = 0; k < 16; ++k) { wih[k] = w_ih[g * 16 + k]; whh[k] = w_hh[g * 16 + k]; }
    const float bg = bias[g];
    #pragma unroll
    for (int k = 0; k < 16; ++k) h[k] = 0.0f;
    float c = 0.0f;
    const int j = g & 15;
    const bool isg = (g >= 32) && (g < 48);
    float xv[16];
    #pragma unroll
    for (int q = 0; q < 4; ++q) *(float4*)&xv[q * 4] = *(const float4*)&in_lds[q * 4];
    for (int t = 0; t < T_STEPS; ++t) {
        float xn[16];
        if (t + 1 < T_STEPS) {
            #pragma unroll
            for (int q = 0; q < 4; ++q)
                *(float4*)&xn[q * 4] = *(const float4*)&in_lds[(t + 1) * 16 + q * 4];
        } else {
            #pragma unroll
            for (int k = 0; k < 16; ++k) xn[k] = 0.0f;
        }
        // input projection first (independent of h -> issues while prior step drains)
        float b0 = fmaf(wih[0], xv[0], bg);
        float b1 = wih[1] * xv[1];
        float b2 = wih[2] * xv[2];
        float b3 = wih[3] * xv[3];
        #pragma unroll
        for (int k = 4; k < 16; k += 4) {
            b0 = fmaf(wih[k + 0], xv[k + 0], b0);
            b1 = fmaf(wih[k + 1], xv[k + 1], b1);
            b2 = fmaf(wih[k + 2], xv[k + 2], b2);
            b3 = fmaf(wih[k + 3], xv[k + 3], b3);
        }
        float s0 = fmaf(whh[0], h[0], (b0 + b1) + (b2 + b3));
        float s1 = whh[1] * h[1];
        float s2 = whh[2] * h[2];
        float s3 = whh[3] * h[3];
        #pragma unroll
        for (int k = 4; k < 16; k += 4) {
            s0 = fmaf(whh[k + 0], h[k + 0], s0);
            s1 = fmaf(whh[k + 1], h[k + 1], s1);
            s2 = fmaf(whh[k + 2], h[k + 2], s2);
            s3 = fmaf(whh[k + 3], h[k + 3], s3);
        }
        float acc = (s0 + s1) + (s2 + s3);
        lstm_step_tail(acc, c, j, isg, h, out_lds, t, g, STORE);
        #pragma unroll
        for (int k = 0; k < 16; ++k) xv[k] = xn[k];
    }
}

__global__ __launch_bounds__(64) void mega_scan(
    const float* __restrict__ pre0, const float* __restrict__ w_hh0,
    const float* __restrict__ w_ih1, const float* __restrict__ w_hh1, const float* __restrict__ b1,
    const float* __restrict__ w_ih2, const float* __restrict__ w_hh2, const float* __restrict__ b2,
    const float* __restrict__ w_ih3, const float* __restrict__ w_hh3, const float* __restrict__ b3,
    const float* __restrict__ w_fc1, const float* __restrict__ b_fc1,
    const float* __restrict__ w_fc2, const float* __restrict__ b_fc2,
    float* __restrict__ out)
{
    __shared__ float seqA[T_STEPS * 16];
    __shared__ float seqB[T_STEPS * 16];
    const int b = blockIdx.x;
    const int g = threadIdx.x;
    float h[16];

    scan_pre_layer(pre0 + (long)b * T_STEPS * 64, seqA, w_hh0, g, h);
    scan_lds_layer<true >(seqA, seqB, w_ih1, w_hh1, b1, g, h);
    scan_lds_layer<true >(seqB, seqA, w_ih2, w_hh2, b2, g, h);
    scan_lds_layer<false>(seqA, nullptr, w_ih3, w_hh3, b3, g, h);

    // ---- head: fc1+relu -> fc2 -> softmax(15). h[0..15] is uniform (SGPR).
    if (g < 16) {
        float a1 = b_fc1[g];
        #pragma unroll
        for (int k = 0; k < 16; ++k) a1 = fmaf(w_fc1[g * 16 + k], h[k], a1);
        a1 = fmaxf(a1, 0.0f);
        float h1[16];
        #pragma unroll
        for (int k = 0; k < 16; ++k) h1[k] = rl_f(a1, k);
        float lg = -3.0e38f;
        if (g < 15) {
            lg = b_fc2[g];
            #pragma unroll
            for (int k = 0; k < 16; ++k) lg = fmaf(w_fc2[g * 16 + k], h1[k], lg);
        }
        float mx = lg;
        #pragma unroll
        for (int d = 8; d >= 1; d >>= 1) mx = fmaxf(mx, __shfl_xor(mx, d, 16));
        float ev = (g < 15) ? exp2f(1.4426950408889634f * (lg - mx)) : 0.0f;
        float sm = ev;
        #pragma unroll
        for (int d = 8; d >= 1; d >>= 1) sm += __shfl_xor(sm, d, 16);
        if (g < 15) out[b * 15 + g] = ev * __builtin_amdgcn_rcpf(sm);
    }
}

extern "C" void kernel_launch(void* const* d_in, const int* in_sizes, int n_in,
                              void* d_out, int out_size, void* d_ws, size_t ws_size,
                              hipStream_t stream) {
    const float* x    = (const float*)d_in[0];
    const float* wih0 = (const float*)d_in[1];
    const float* whh0 = (const float*)d_in[2];
    const float* b0   = (const float*)d_in[3];
    const float* wih1 = (const float*)d_in[4];
    const float* whh1 = (const float*)d_in[5];
    const float* b1   = (const float*)d_in[6];
    const float* wih2 = (const float*)d_in[7];
    const float* whh2 = (const float*)d_in[8];
    const float* b2   = (const float*)d_in[9];
    const float* wih3 = (const float*)d_in[10];
    const float* whh3 = (const float*)d_in[11];
    const float* b3   = (const float*)d_in[12];
    const float* wfc1 = (const float*)d_in[13];
    const float* bfc1 = (const float*)d_in[14];
    const float* wfc2 = (const float*)d_in[15];
    const float* bfc2 = (const float*)d_in[16];

    float* pre0 = (float*)d_ws;   // 51200*64*4 = 13,107,200 B

    pre0_gemm<<<dim3(400), dim3(256), 0, stream>>>(x, wih0, b0, pre0);
    mega_scan<<<dim3(256), dim3(64), 0, stream>>>(pre0, whh0,
        wih1, whh1, b1, wih2, whh2, b2, wih3, whh3, b3,
        wfc1, bfc1, wfc2, bfc2, (float*)d_out);
}

// Round 2
// 254.943 us; speedup vs baseline: 1.0881x; 1.0881x over previous
//
#include <hip/hip_runtime.h>

#define T_STEPS 200
#define IN_DIM 1086

using f32x4v = __attribute__((ext_vector_type(4))) float;
using bf16x8 = __attribute__((ext_vector_type(8))) short;
using u32x4  = __attribute__((ext_vector_type(4))) unsigned int;
typedef unsigned uv2 __attribute__((ext_vector_type(2)));

#if __has_builtin(__builtin_amdgcn_permlane16_swap) && __has_builtin(__builtin_amdgcn_permlane32_swap)
#define HAVE_PERMLANE_SWAP 1
#else
#define HAVE_PERMLANE_SWAP 0
#endif

__device__ __forceinline__ float rl_f(float v, int lane) {
    return __uint_as_float((unsigned)__builtin_amdgcn_readlane((int)__float_as_uint(v), lane));
}

// ---------------------------------------------------------------------------
// pre0 = x @ W_ih0^T + b0   (unchanged from R1 — known correct, ~70us, revisit
// after the scan is fixed)
// ---------------------------------------------------------------------------
__global__ __launch_bounds__(256) void pre0_gemm(
    const float* __restrict__ X, const float* __restrict__ W,
    const float* __restrict__ bias, float* __restrict__ out)
{
    __shared__ unsigned short AhL[4][128][8];
    __shared__ unsigned short AlL[4][128][8];
    __shared__ unsigned short BhL[4][64][8];
    __shared__ unsigned short BlL[4][64][8];

    const int tid  = threadIdx.x;
    const int lane = tid & 63;
    const int wv   = tid >> 6;
    const long m0  = (long)blockIdx.x * 128;

    const int sr  = tid >> 1;
    const int skb = (tid & 1) * 16;
    const int wr  = sr & 63;
    const float* xsrc = X + (m0 + sr) * (long)IN_DIM + skb;
    const float* wsrc = W + (long)wr * IN_DIM + skb;

    const int fr = lane & 15;
    const int kg = lane >> 4;

    f32x4v acc[2][4];
    #pragma unroll
    for (int mf = 0; mf < 2; ++mf)
        #pragma unroll
        for (int nf = 0; nf < 4; ++nf)
            #pragma unroll
            for (int r = 0; r < 4; ++r) acc[mf][nf][r] = 0.0f;

    for (int k0 = 0; k0 < IN_DIM; k0 += 32) {
        float xv[16];
        #pragma unroll
        for (int j = 0; j < 16; j += 2) {
            int k = k0 + skb + j;
            if (k + 2 <= IN_DIM) {
                float2 t = *(const float2*)(xsrc + k0 + j);
                xv[j] = t.x; xv[j + 1] = t.y;
            } else { xv[j] = 0.0f; xv[j + 1] = 0.0f; }
        }
        float wvv[16];
        if (tid < 128) {
            #pragma unroll
            for (int j = 0; j < 16; j += 2) {
                int k = k0 + skb + j;
                if (k + 2 <= IN_DIM) {
                    float2 t = *(const float2*)(wsrc + k0 + j);
                    wvv[j] = t.x; wvv[j + 1] = t.y;
                } else { wvv[j] = 0.0f; wvv[j + 1] = 0.0f; }
            }
        }
        __syncthreads();

        #pragma unroll
        for (int q = 0; q < 2; ++q) {
            u32x4 hw, lw;
            #pragma unroll
            for (int p = 0; p < 4; ++p) {
                float a0 = xv[q * 8 + 2 * p], a1 = xv[q * 8 + 2 * p + 1];
                unsigned u0 = __float_as_uint(a0), u1 = __float_as_uint(a1);
                unsigned h0 = u0 & 0xffff0000u, h1 = u1 & 0xffff0000u;
                hw[p] = (u0 >> 16) | h1;
                float l0 = a0 - __uint_as_float(h0);
                float l1 = a1 - __uint_as_float(h1);
                lw[p] = (__float_as_uint(l0) >> 16) | (__float_as_uint(l1) & 0xffff0000u);
            }
            int kgs = (tid & 1) * 2 + q;
            *(u32x4*)&AhL[kgs][sr][0] = hw;
            *(u32x4*)&AlL[kgs][sr][0] = lw;
        }
        if (tid < 128) {
            #pragma unroll
            for (int q = 0; q < 2; ++q) {
                u32x4 hw, lw;
                #pragma unroll
                for (int p = 0; p < 4; ++p) {
                    float a0 = wvv[q * 8 + 2 * p], a1 = wvv[q * 8 + 2 * p + 1];
                    unsigned u0 = __float_as_uint(a0), u1 = __float_as_uint(a1);
                    unsigned h0 = u0 & 0xffff0000u, h1 = u1 & 0xffff0000u;
                    hw[p] = (u0 >> 16) | h1;
                    float l0 = a0 - __uint_as_float(h0);
                    float l1 = a1 - __uint_as_float(h1);
                    lw[p] = (__float_as_uint(l0) >> 16) | (__float_as_uint(l1) & 0xffff0000u);
                }
                int kgs = (tid & 1) * 2 + q;
                *(u32x4*)&BhL[kgs][wr][0] = hw;
                *(u32x4*)&BlL[kgs][wr][0] = lw;
            }
        }
        __syncthreads();

        bf16x8 ah[2], al[2], bh[4], bl[4];
        #pragma unroll
        for (int mf = 0; mf < 2; ++mf) {
            ah[mf] = *(const bf16x8*)&AhL[kg][wv * 32 + mf * 16 + fr][0];
            al[mf] = *(const bf16x8*)&AlL[kg][wv * 32 + mf * 16 + fr][0];
        }
        #pragma unroll
        for (int nf = 0; nf < 4; ++nf) {
            bh[nf] = *(const bf16x8*)&BhL[kg][nf * 16 + fr][0];
            bl[nf] = *(const bf16x8*)&BlL[kg][nf * 16 + fr][0];
        }
        #pragma unroll
        for (int mf = 0; mf < 2; ++mf)
            #pragma unroll
            for (int nf = 0; nf < 4; ++nf) {
                acc[mf][nf] = __builtin_amdgcn_mfma_f32_16x16x32_bf16(ah[mf], bh[nf], acc[mf][nf], 0, 0, 0);
                acc[mf][nf] = __builtin_amdgcn_mfma_f32_16x16x32_bf16(al[mf], bh[nf], acc[mf][nf], 0, 0, 0);
                acc[mf][nf] = __builtin_amdgcn_mfma_f32_16x16x32_bf16(ah[mf], bl[nf], acc[mf][nf], 0, 0, 0);
            }
    }

    float bvv[4];
    #pragma unroll
    for (int nf = 0; nf < 4; ++nf) bvv[nf] = bias[nf * 16 + fr];
    #pragma unroll
    for (int mf = 0; mf < 2; ++mf)
        #pragma unroll
        for (int nf = 0; nf < 4; ++nf)
            #pragma unroll
            for (int r = 0; r < 4; ++r) {
                long row = m0 + wv * 32 + mf * 16 + kg * 4 + r;
                out[row * 64 + nf * 16 + fr] = acc[mf][nf][r] + bvv[nf];
            }
}

// ---------------------------------------------------------------------------
// Scan: one wave per batch. Lane g owns gate g (i:0-15 f:16-31 g:32-47 o:48-63).
// Gate gather via v_permlane{16,32}_swap (VALU, ~6cy) instead of ds_bpermute
// (~120cy). Only lanes 0-15 need valid c/h; h broadcast via 16 readlanes.
// ---------------------------------------------------------------------------
__device__ __forceinline__ float dot16(const float* __restrict__ w, const float h[16], float init) {
    float s0 = fmaf(w[0], h[0], init);
    float s1 = w[1] * h[1];
    float s2 = w[2] * h[2];
    float s3 = w[3] * h[3];
    #pragma unroll
    for (int k = 4; k < 16; k += 4) {
        s0 = fmaf(w[k + 0], h[k + 0], s0);
        s1 = fmaf(w[k + 1], h[k + 1], s1);
        s2 = fmaf(w[k + 2], h[k + 2], s2);
        s3 = fmaf(w[k + 3], h[k + 3], s3);
    }
    return (s0 + s1) + (s2 + s3);
}

template<bool STORE>
__device__ __forceinline__ void step_tail(
    float acc, float escale, float am, float aa, float& c,
    bool sel16, bool sel32, float h[16], float* st, bool lt16)
{
    // gate activation: sigmoid (i,f,o) or tanh (g), selected by per-lane consts
    float e = exp2f(escale * acc);
    float s = __builtin_amdgcn_rcpf(1.0f + e);
    float a = fmaf(am, s, aa);
    // gather f,g,o into lanes 0-15 (other lanes junk — fine)
#if HAVE_PERMLANE_SWAP
    unsigned au = __float_as_uint(a);
    uv2 r16 = __builtin_amdgcn_permlane16_swap(au, au, false, false);
    uv2 r32 = __builtin_amdgcn_permlane32_swap(au, au, false, false);
    unsigned fvu = sel16 ? r16[1] : r16[0];
    unsigned gvu = sel32 ? r32[1] : r32[0];
    uv2 r48 = __builtin_amdgcn_permlane16_swap(gvu, gvu, false, false);
    unsigned ovu = sel16 ? r48[1] : r48[0];
    float fv = __uint_as_float(fvu);
    float gv = __uint_as_float(gvu);
    float ov = __uint_as_float(ovu);
#else
    float fv = __shfl_xor(a, 16, 64);
    float gv = __shfl_xor(a, 32, 64);
    float ov = __shfl_xor(a, 48, 64);
#endif
    c = fmaf(fv, c, a * gv);               // a == i in lanes 0-15
    float e2 = exp2f(-2.8853900817779268f * c);
    float s2 = __builtin_amdgcn_rcpf(1.0f + e2);
    float ov2 = ov + ov;
    float hn = fmaf(ov2, s2, -ov);         // ov * tanh(c)
    if (STORE && lt16) *st = hn;
    #pragma unroll
    for (int k = 0; k < 16; ++k) h[k] = rl_f(hn, k);
}

// layer 0a: pre-activations from global (bias folded by GEMM), prefetch dist 4
__device__ __forceinline__ void scan_pre_layer(
    const float* __restrict__ pre, float* out_lds,
    const float* __restrict__ w_hh, const int g,
    bool sel16, bool sel32, float h[16])
{
    float whh[16];
    #pragma unroll
    for (int k = 0; k < 16; ++k) whh[k] = w_hh[g * 16 + k];
    #pragma unroll
    for (int k = 0; k < 16; ++k) h[k] = 0.0f;
    float c = 0.0f;
    const bool lt16 = g < 16;
    const int q = g >> 4;
    const float escale = (q == 2) ? -2.8853900817779268f : -1.4426950408889634f;
    const float am = (q == 2) ? 2.0f : 1.0f;
    const float aa = (q == 2) ? -1.0f : 0.0f;
    const float* pb = pre + g;
    float pf[4] = { pb[0], pb[64], pb[128], pb[192] };
    for (int t = 0; t < T_STEPS; t += 4) {
        #pragma unroll
        for (int u = 0; u < 4; ++u) {
            int tn = t + 4 + u; tn = tn < T_STEPS ? tn : T_STEPS - 1;
            float pn = pb[tn * 64];                 // clamped prefetch, off-chain
            float acc = dot16(whh, h, pf[u]);
            step_tail<true>(acc, escale, am, aa, c, sel16, sel32, h,
                            out_lds + (t + u) * 16 + g, lt16);
            pf[u] = pn;
        }
    }
}

// layers 0b/1a/1b: input sequence from LDS, w_ih fused
template<bool STORE>
__device__ __forceinline__ void scan_lds_layer(
    const float* in_lds, float* out_lds,
    const float* __restrict__ w_ih, const float* __restrict__ w_hh,
    const float* __restrict__ bias, const int g,
    bool sel16, bool sel32, float h[16])
{
    float wih[16], whh[16];
    #pragma unroll
    for (int k = 0; k < 16; ++k) { wih[k] = w_ih[g * 16 + k]; whh[k] = w_hh[g * 16 + k]; }
    const float bg = bias[g];
    #pragma unroll
    for (int k = 0; k < 16; ++k) h[k] = 0.0f;
    float c = 0.0f;
    const bool lt16 = g < 16;
    const int q = g >> 4;
    const float escale = (q == 2) ? -2.8853900817779268f : -1.4426950408889634f;
    const float am = (q == 2) ? 2.0f : 1.0f;
    const float aa = (q == 2) ? -1.0f : 0.0f;
    float xv[16];
    #pragma unroll
    for (int qq = 0; qq < 4; ++qq) *(float4*)&xv[qq * 4] = *(const float4*)&in_lds[qq * 4];
    for (int t = 0; t < T_STEPS; ++t) {
        int tn = t + 1 < T_STEPS ? t + 1 : T_STEPS - 1;   // clamped prefetch
        float xn[16];
        #pragma unroll
        for (int qq = 0; qq < 4; ++qq)
            *(float4*)&xn[qq * 4] = *(const float4*)&in_lds[tn * 16 + qq * 4];
        // input projection (independent of h — overlaps prior step's tail)
        float b0 = fmaf(wih[0], xv[0], bg);
        float b1 = wih[1] * xv[1];
        float b2 = wih[2] * xv[2];
        float b3 = wih[3] * xv[3];
        #pragma unroll
        for (int k = 4; k < 16; k += 4) {
            b0 = fmaf(wih[k + 0], xv[k + 0], b0);
            b1 = fmaf(wih[k + 1], xv[k + 1], b1);
            b2 = fmaf(wih[k + 2], xv[k + 2], b2);
            b3 = fmaf(wih[k + 3], xv[k + 3], b3);
        }
        float acc = dot16(whh, h, (b0 + b1) + (b2 + b3));
        step_tail<STORE>(acc, escale, am, aa, c, sel16, sel32, h,
                         STORE ? (out_lds + t * 16 + g) : nullptr, lt16);
        #pragma unroll
        for (int k = 0; k < 16; ++k) xv[k] = xn[k];
    }
}

__global__ __launch_bounds__(64) void mega_scan(
    const float* __restrict__ pre0, const float* __restrict__ w_hh0,
    const float* __restrict__ w_ih1, const float* __restrict__ w_hh1, const float* __restrict__ b1,
    const float* __restrict__ w_ih2, const float* __restrict__ w_hh2, const float* __restrict__ b2,
    const float* __restrict__ w_ih3, const float* __restrict__ w_hh3, const float* __restrict__ b3,
    const float* __restrict__ w_fc1, const float* __restrict__ b_fc1,
    const float* __restrict__ w_fc2, const float* __restrict__ b_fc2,
    float* __restrict__ out)
{
    __shared__ float seqA[T_STEPS * 16];
    __shared__ float seqB[T_STEPS * 16];
    const int b = blockIdx.x;
    const int g = threadIdx.x;

    // one-time probe: which output word of permlane*_swap holds the partner
    bool sel16 = false, sel32 = false;
#if HAVE_PERMLANE_SWAP
    {
        uv2 q16 = __builtin_amdgcn_permlane16_swap((unsigned)g, (unsigned)g, false, false);
        sel16 = (__builtin_amdgcn_readfirstlane((int)q16[1]) == 16);
        uv2 q32 = __builtin_amdgcn_permlane32_swap((unsigned)g, (unsigned)g, false, false);
        sel32 = (__builtin_amdgcn_readfirstlane((int)q32[1]) == 32);
    }
#endif

    float h[16];
    scan_pre_layer(pre0 + (long)b * T_STEPS * 64, seqA, w_hh0, g, sel16, sel32, h);
    scan_lds_layer<true >(seqA, seqB, w_ih1, w_hh1, b1, g, sel16, sel32, h);
    scan_lds_layer<true >(seqB, seqA, w_ih2, w_hh2, b2, g, sel16, sel32, h);
    scan_lds_layer<false>(seqA, nullptr, w_ih3, w_hh3, b3, g, sel16, sel32, h);

    // ---- head: fc1+relu -> fc2 -> softmax(15)
    if (g < 16) {
        float a1 = b_fc1[g];
        #pragma unroll
        for (int k = 0; k < 16; ++k) a1 = fmaf(w_fc1[g * 16 + k], h[k], a1);
        a1 = fmaxf(a1, 0.0f);
        float h1[16];
        #pragma unroll
        for (int k = 0; k < 16; ++k) h1[k] = rl_f(a1, k);
        float lg = -3.0e38f;
        if (g < 15) {
            lg = b_fc2[g];
            #pragma unroll
            for (int k = 0; k < 16; ++k) lg = fmaf(w_fc2[g * 16 + k], h1[k], lg);
        }
        float mx = lg;
        #pragma unroll
        for (int d = 8; d >= 1; d >>= 1) mx = fmaxf(mx, __shfl_xor(mx, d, 16));
        float ev = (g < 15) ? exp2f(1.4426950408889634f * (lg - mx)) : 0.0f;
        float sm = ev;
        #pragma unroll
        for (int d = 8; d >= 1; d >>= 1) sm += __shfl_xor(sm, d, 16);
        if (g < 15) out[b * 15 + g] = ev * __builtin_amdgcn_rcpf(sm);
    }
}

extern "C" void kernel_launch(void* const* d_in, const int* in_sizes, int n_in,
                              void* d_out, int out_size, void* d_ws, size_t ws_size,
                              hipStream_t stream) {
    const float* x    = (const float*)d_in[0];
    const float* wih0 = (const float*)d_in[1];
    const float* whh0 = (const float*)d_in[2];
    const float* b0   = (const float*)d_in[3];
    const float* wih1 = (const float*)d_in[4];
    const float* whh1 = (const float*)d_in[5];
    const float* b1   = (const float*)d_in[6];
    const float* wih2 = (const float*)d_in[7];
    const float* whh2 = (const float*)d_in[8];
    const float* b2   = (const float*)d_in[9];
    const float* wih3 = (const float*)d_in[10];
    const float* whh3 = (const float*)d_in[11];
    const float* b3   = (const float*)d_in[12];
    const float* wfc1 = (const float*)d_in[13];
    const float* bfc1 = (const float*)d_in[14];
    const float* wfc2 = (const float*)d_in[15];
    const float* bfc2 = (const float*)d_in[16];

    float* pre0 = (float*)d_ws;   // 51200*64*4 = 13,107,200 B

    pre0_gemm<<<dim3(400), dim3(256), 0, stream>>>(x, wih0, b0, pre0);
    mega_scan<<<dim3(256), dim3(64), 0, stream>>>(pre0, whh0,
        wih1, whh1, b1, wih2, whh2, b2, wih3, whh3, b3,
        wfc1, bfc1, wfc2, bfc2, (float*)d_out);
}

// Round 3
// 190.577 us; speedup vs baseline: 1.4556x; 1.3377x over previous
//
#include <hip/hip_runtime.h>

#define T_STEPS 200
#define IN_DIM 1086

using f32x4v = __attribute__((ext_vector_type(4))) float;
using bf16x8 = __attribute__((ext_vector_type(8))) short;
using u32x4  = __attribute__((ext_vector_type(4))) unsigned int;
typedef unsigned uv2 __attribute__((ext_vector_type(2)));

#if __has_builtin(__builtin_amdgcn_permlane16_swap) && __has_builtin(__builtin_amdgcn_permlane32_swap)
#define HAVE_PERMLANE_SWAP 1
#else
#define HAVE_PERMLANE_SWAP 0
#endif

#if __has_builtin(__builtin_amdgcn_exp2f)
#define EXP2F(x) __builtin_amdgcn_exp2f(x)
#else
#define EXP2F(x) exp2f(x)
#endif

__device__ __forceinline__ float rl_f(float v, int lane) {
    return __uint_as_float((unsigned)__builtin_amdgcn_readlane((int)__float_as_uint(v), lane));
}

// ---------------------------------------------------------------------------
// pre0 = x @ W_ih0^T + b0  (unchanged — ~70us; becomes the top dispatch after
// this round's scan fix; optimize next round with its counters)
// ---------------------------------------------------------------------------
__global__ __launch_bounds__(256) void pre0_gemm(
    const float* __restrict__ X, const float* __restrict__ W,
    const float* __restrict__ bias, float* __restrict__ out)
{
    __shared__ unsigned short AhL[4][128][8];
    __shared__ unsigned short AlL[4][128][8];
    __shared__ unsigned short BhL[4][64][8];
    __shared__ unsigned short BlL[4][64][8];

    const int tid  = threadIdx.x;
    const int lane = tid & 63;
    const int wv   = tid >> 6;
    const long m0  = (long)blockIdx.x * 128;

    const int sr  = tid >> 1;
    const int skb = (tid & 1) * 16;
    const int wr  = sr & 63;
    const float* xsrc = X + (m0 + sr) * (long)IN_DIM + skb;
    const float* wsrc = W + (long)wr * IN_DIM + skb;

    const int fr = lane & 15;
    const int kg = lane >> 4;

    f32x4v acc[2][4];
    #pragma unroll
    for (int mf = 0; mf < 2; ++mf)
        #pragma unroll
        for (int nf = 0; nf < 4; ++nf)
            #pragma unroll
            for (int r = 0; r < 4; ++r) acc[mf][nf][r] = 0.0f;

    for (int k0 = 0; k0 < IN_DIM; k0 += 32) {
        float xv[16];
        #pragma unroll
        for (int j = 0; j < 16; j += 2) {
            int k = k0 + skb + j;
            if (k + 2 <= IN_DIM) {
                float2 t = *(const float2*)(xsrc + k0 + j);
                xv[j] = t.x; xv[j + 1] = t.y;
            } else { xv[j] = 0.0f; xv[j + 1] = 0.0f; }
        }
        float wvv[16];
        if (tid < 128) {
            #pragma unroll
            for (int j = 0; j < 16; j += 2) {
                int k = k0 + skb + j;
                if (k + 2 <= IN_DIM) {
                    float2 t = *(const float2*)(wsrc + k0 + j);
                    wvv[j] = t.x; wvv[j + 1] = t.y;
                } else { wvv[j] = 0.0f; wvv[j + 1] = 0.0f; }
            }
        }
        __syncthreads();

        #pragma unroll
        for (int q = 0; q < 2; ++q) {
            u32x4 hw, lw;
            #pragma unroll
            for (int p = 0; p < 4; ++p) {
                float a0 = xv[q * 8 + 2 * p], a1 = xv[q * 8 + 2 * p + 1];
                unsigned u0 = __float_as_uint(a0), u1 = __float_as_uint(a1);
                unsigned h0 = u0 & 0xffff0000u, h1 = u1 & 0xffff0000u;
                hw[p] = (u0 >> 16) | h1;
                float l0 = a0 - __uint_as_float(h0);
                float l1 = a1 - __uint_as_float(h1);
                lw[p] = (__float_as_uint(l0) >> 16) | (__float_as_uint(l1) & 0xffff0000u);
            }
            int kgs = (tid & 1) * 2 + q;
            *(u32x4*)&AhL[kgs][sr][0] = hw;
            *(u32x4*)&AlL[kgs][sr][0] = lw;
        }
        if (tid < 128) {
            #pragma unroll
            for (int q = 0; q < 2; ++q) {
                u32x4 hw, lw;
                #pragma unroll
                for (int p = 0; p < 4; ++p) {
                    float a0 = wvv[q * 8 + 2 * p], a1 = wvv[q * 8 + 2 * p + 1];
                    unsigned u0 = __float_as_uint(a0), u1 = __float_as_uint(a1);
                    unsigned h0 = u0 & 0xffff0000u, h1 = u1 & 0xffff0000u;
                    hw[p] = (u0 >> 16) | h1;
                    float l0 = a0 - __uint_as_float(h0);
                    float l1 = a1 - __uint_as_float(h1);
                    lw[p] = (__float_as_uint(l0) >> 16) | (__float_as_uint(l1) & 0xffff0000u);
                }
                int kgs = (tid & 1) * 2 + q;
                *(u32x4*)&BhL[kgs][wr][0] = hw;
                *(u32x4*)&BlL[kgs][wr][0] = lw;
            }
        }
        __syncthreads();

        bf16x8 ah[2], al[2], bh[4], bl[4];
        #pragma unroll
        for (int mf = 0; mf < 2; ++mf) {
            ah[mf] = *(const bf16x8*)&AhL[kg][wv * 32 + mf * 16 + fr][0];
            al[mf] = *(const bf16x8*)&AlL[kg][wv * 32 + mf * 16 + fr][0];
        }
        #pragma unroll
        for (int nf = 0; nf < 4; ++nf) {
            bh[nf] = *(const bf16x8*)&BhL[kg][nf * 16 + fr][0];
            bl[nf] = *(const bf16x8*)&BlL[kg][nf * 16 + fr][0];
        }
        #pragma unroll
        for (int mf = 0; mf < 2; ++mf)
            #pragma unroll
            for (int nf = 0; nf < 4; ++nf) {
                acc[mf][nf] = __builtin_amdgcn_mfma_f32_16x16x32_bf16(ah[mf], bh[nf], acc[mf][nf], 0, 0, 0);
                acc[mf][nf] = __builtin_amdgcn_mfma_f32_16x16x32_bf16(al[mf], bh[nf], acc[mf][nf], 0, 0, 0);
                acc[mf][nf] = __builtin_amdgcn_mfma_f32_16x16x32_bf16(ah[mf], bl[nf], acc[mf][nf], 0, 0, 0);
            }
    }

    float bvv[4];
    #pragma unroll
    for (int nf = 0; nf < 4; ++nf) bvv[nf] = bias[nf * 16 + fr];
    #pragma unroll
    for (int mf = 0; mf < 2; ++mf)
        #pragma unroll
        for (int nf = 0; nf < 4; ++nf)
            #pragma unroll
            for (int r = 0; r < 4; ++r) {
                long row = m0 + wv * 32 + mf * 16 + kg * 4 + r;
                out[row * 64 + nf * 16 + fr] = acc[mf][nf][r] + bvv[nf];
            }
}

// ---------------------------------------------------------------------------
// mega_scan: 4-wave layer pipeline. Block = batch element, wave w = layer w,
// tick tau: wave w computes t = tau - w; h flows wave->wave via LDS with one
// __syncthreads per tick. 203 ticks instead of 800 sequential steps.
// Within a wave: lane g owns gate g; gather via permlane swaps; h broadcast
// via 16 readlanes (SGPRs).
// ---------------------------------------------------------------------------
__global__ __launch_bounds__(256) void mega_scan(
    const float* __restrict__ pre0, const float* __restrict__ whh0,
    const float* __restrict__ wih1, const float* __restrict__ whh1, const float* __restrict__ b1,
    const float* __restrict__ wih2, const float* __restrict__ whh2, const float* __restrict__ b2,
    const float* __restrict__ wih3, const float* __restrict__ whh3, const float* __restrict__ b3,
    const float* __restrict__ w_fc1, const float* __restrict__ b_fc1,
    const float* __restrict__ w_fc2, const float* __restrict__ b_fc2,
    float* __restrict__ out)
{
    __shared__ float buf[3][T_STEPS][16];   // 38400 B

    const int b    = blockIdx.x;
    const int tid  = threadIdx.x;
    const int g    = tid & 63;
    const int wv   = tid >> 6;

    // one-time probe: which output word of permlane*_swap holds the partner
    bool sel16 = false, sel32 = false;
#if HAVE_PERMLANE_SWAP
    {
        uv2 q16 = __builtin_amdgcn_permlane16_swap((unsigned)g, (unsigned)g, false, false);
        sel16 = (__builtin_amdgcn_readfirstlane((int)q16[1]) == 16);
        uv2 q32 = __builtin_amdgcn_permlane32_swap((unsigned)g, (unsigned)g, false, false);
        sel32 = (__builtin_amdgcn_readfirstlane((int)q32[1]) == 32);
    }
#endif

    // per-wave layer weights
    const float* wih = nullptr; const float* whh; const float* bias = nullptr;
    if      (wv == 0) { whh = whh0; }
    else if (wv == 1) { wih = wih1; whh = whh1; bias = b1; }
    else if (wv == 2) { wih = wih2; whh = whh2; bias = b2; }
    else              { wih = wih3; whh = whh3; bias = b3; }

    float whh_r[16];
    #pragma unroll
    for (int q = 0; q < 4; ++q)
        *(float4*)&whh_r[q * 4] = *(const float4*)&whh[g * 16 + q * 4];
    float wih_r[16]; float bg = 0.0f;
    if (wv) {
        #pragma unroll
        for (int q = 0; q < 4; ++q)
            *(float4*)&wih_r[q * 4] = *(const float4*)&wih[g * 16 + q * 4];
        bg = bias[g];
    }

    // wave0 pre-activation pipeline (distance-2 prefetch)
    const float* pb = pre0 + (long)b * T_STEPS * 64 + g;
    float pc = 0.0f, p1 = 0.0f, p2 = 0.0f;
    if (wv == 0) { pc = pb[0]; p1 = pb[64]; p2 = pb[128]; }

    float hs[16];
    #pragma unroll
    for (int k = 0; k < 16; ++k) hs[k] = 0.0f;
    float c = 0.0f;

    const int q4 = g >> 4;
    const float escale = (q4 == 2) ? -2.8853900817779268f : -1.4426950408889634f;
    const float am = (q4 == 2) ? 2.0f : 1.0f;
    const float aa = (q4 == 2) ? -1.0f : 0.0f;

    for (int tau = 0; tau < T_STEPS + 3; ++tau) {
        __syncthreads();
        const int t = tau - wv;
        if (t >= 0 && t < T_STEPS) {
            // x from previous layer (uniform-address LDS broadcast), wv>=1
            float xr[16];
            if (wv) {
                #pragma unroll
                for (int q = 0; q < 4; ++q)
                    *(float4*)&xr[q * 4] = *(const float4*)&buf[wv - 1][t][q * 4];
            }
            // recurrent dot on SGPR h — overlaps the LDS read latency
            float r0 = fmaf(whh_r[0], hs[0], wv ? bg : pc);
            float r1 = whh_r[1] * hs[1];
            float r2 = whh_r[2] * hs[2];
            float r3 = whh_r[3] * hs[3];
            #pragma unroll
            for (int k = 4; k < 16; k += 4) {
                r0 = fmaf(whh_r[k + 0], hs[k + 0], r0);
                r1 = fmaf(whh_r[k + 1], hs[k + 1], r1);
                r2 = fmaf(whh_r[k + 2], hs[k + 2], r2);
                r3 = fmaf(whh_r[k + 3], hs[k + 3], r3);
            }
            float acc = (r0 + r1) + (r2 + r3);
            if (wv) {
                float p0 = wih_r[0] * xr[0];
                float q1 = wih_r[1] * xr[1];
                float q2 = wih_r[2] * xr[2];
                float q3 = wih_r[3] * xr[3];
                #pragma unroll
                for (int k = 4; k < 16; k += 4) {
                    p0 = fmaf(wih_r[k + 0], xr[k + 0], p0);
                    q1 = fmaf(wih_r[k + 1], xr[k + 1], q1);
                    q2 = fmaf(wih_r[k + 2], xr[k + 2], q2);
                    q3 = fmaf(wih_r[k + 3], xr[k + 3], q3);
                }
                acc += (p0 + q1) + (q2 + q3);
            }
            // activation: sigmoid (i,f,o) / tanh (g) via per-lane constants
            float e = EXP2F(escale * acc);
            float s = __builtin_amdgcn_rcpf(1.0f + e);
            float a = fmaf(am, s, aa);
            // gather f,g,o into lanes 0-15
#if HAVE_PERMLANE_SWAP
            unsigned au = __float_as_uint(a);
            uv2 r16 = __builtin_amdgcn_permlane16_swap(au, au, false, false);
            uv2 r32 = __builtin_amdgcn_permlane32_swap(au, au, false, false);
            unsigned fvu = sel16 ? r16[1] : r16[0];
            unsigned gvu = sel32 ? r32[1] : r32[0];
            uv2 r48 = __builtin_amdgcn_permlane16_swap(gvu, gvu, false, false);
            unsigned ovu = sel16 ? r48[1] : r48[0];
            float fv = __uint_as_float(fvu);
            float gv = __uint_as_float(gvu);
            float ov = __uint_as_float(ovu);
#else
            float fv = __shfl_xor(a, 16, 64);
            float gv = __shfl_xor(a, 32, 64);
            float ov = __shfl_xor(a, 48, 64);
#endif
            c = fmaf(fv, c, a * gv);          // a == i in lanes 0-15
            float e2 = EXP2F(-2.8853900817779268f * c);
            float s2 = __builtin_amdgcn_rcpf(1.0f + e2);
            float hn = fmaf(ov + ov, s2, -ov);  // ov * tanh(c)
            if (wv < 3 && g < 16) buf[wv][t][g] = hn;
            #pragma unroll
            for (int k = 0; k < 16; ++k) hs[k] = rl_f(hn, k);
            if (wv == 0) {
                pc = p1; p1 = p2;
                int tn = t + 3; tn = tn < T_STEPS ? tn : T_STEPS - 1;
                p2 = pb[(long)tn * 64];
            }
        }
    }

    // ---- head: fc1+relu -> fc2 -> softmax(15), wave3 only
    if (wv == 3 && g < 16) {
        float a1 = b_fc1[g];
        #pragma unroll
        for (int k = 0; k < 16; ++k) a1 = fmaf(w_fc1[g * 16 + k], hs[k], a1);
        a1 = fmaxf(a1, 0.0f);
        float h1[16];
        #pragma unroll
        for (int k = 0; k < 16; ++k) h1[k] = rl_f(a1, k);
        float lg = -3.0e38f;
        if (g < 15) {
            lg = b_fc2[g];
            #pragma unroll
            for (int k = 0; k < 16; ++k) lg = fmaf(w_fc2[g * 16 + k], h1[k], lg);
        }
        float mx = lg;
        #pragma unroll
        for (int d = 8; d >= 1; d >>= 1) mx = fmaxf(mx, __shfl_xor(mx, d, 16));
        float ev = (g < 15) ? EXP2F(1.4426950408889634f * (lg - mx)) : 0.0f;
        float sm = ev;
        #pragma unroll
        for (int d = 8; d >= 1; d >>= 1) sm += __shfl_xor(sm, d, 16);
        if (g < 15) out[b * 15 + g] = ev * __builtin_amdgcn_rcpf(sm);
    }
}

extern "C" void kernel_launch(void* const* d_in, const int* in_sizes, int n_in,
                              void* d_out, int out_size, void* d_ws, size_t ws_size,
                              hipStream_t stream) {
    const float* x    = (const float*)d_in[0];
    const float* wih0 = (const float*)d_in[1];
    const float* whh0 = (const float*)d_in[2];
    const float* b0   = (const float*)d_in[3];
    const float* wih1 = (const float*)d_in[4];
    const float* whh1 = (const float*)d_in[5];
    const float* b1   = (const float*)d_in[6];
    const float* wih2 = (const float*)d_in[7];
    const float* whh2 = (const float*)d_in[8];
    const float* b2   = (const float*)d_in[9];
    const float* wih3 = (const float*)d_in[10];
    const float* whh3 = (const float*)d_in[11];
    const float* b3   = (const float*)d_in[12];
    const float* wfc1 = (const float*)d_in[13];
    const float* bfc1 = (const float*)d_in[14];
    const float* wfc2 = (const float*)d_in[15];
    const float* bfc2 = (const float*)d_in[16];

    float* pre0 = (float*)d_ws;   // 51200*64*4 = 13,107,200 B

    pre0_gemm<<<dim3(400), dim3(256), 0, stream>>>(x, wih0, b0, pre0);
    mega_scan<<<dim3(256), dim3(256), 0, stream>>>(pre0, whh0,
        wih1, whh1, b1, wih2, whh2, b2, wih3, whh3, b3,
        wfc1, bfc1, wfc2, bfc2, (float*)d_out);
}

// Round 4
// 166.596 us; speedup vs baseline: 1.6651x; 1.1439x over previous
//
#include <hip/hip_runtime.h>

#define T_STEPS 200
#define IN_DIM 1086
#define KTILES 34              // ceil(1086/32)
#define M_TOTAL 51200          // 256*200

using f32x4v = __attribute__((ext_vector_type(4))) float;
using bf16x8 = __attribute__((ext_vector_type(8))) short;
using u32x4  = __attribute__((ext_vector_type(4))) unsigned int;
typedef unsigned uv2 __attribute__((ext_vector_type(2)));

#if __has_builtin(__builtin_amdgcn_permlane16_swap) && __has_builtin(__builtin_amdgcn_permlane32_swap)
#define HAVE_PERMLANE_SWAP 1
#else
#define HAVE_PERMLANE_SWAP 0
#endif

#if __has_builtin(__builtin_amdgcn_exp2f)
#define EXP2F(x) __builtin_amdgcn_exp2f(x)
#else
#define EXP2F(x) exp2f(x)
#endif

__device__ __forceinline__ float rl_f(float v, int lane) {
    return __uint_as_float((unsigned)__builtin_amdgcn_readlane((int)__float_as_uint(v), lane));
}

// ---------------------------------------------------------------------------
// prepack_w: W[64][1086] fp32 -> hi/lo bf16 in fragment layout [kt][kg][64][8],
// k zero-padded to 1088. Runs once per call, ~69k threads, negligible.
// ---------------------------------------------------------------------------
__global__ __launch_bounds__(256) void prepack_w(
    const float* __restrict__ W,
    unsigned short* __restrict__ Wh, unsigned short* __restrict__ Wl)
{
    int idx = blockIdx.x * 256 + threadIdx.x;
    if (idx >= KTILES * 4 * 64 * 8) return;
    int j = idx & 7;
    int n = (idx >> 3) & 63;
    int k = (idx >> 9) * 8 + j;          // (kt*4+kg)*8 + j == kt*32 + kg*8 + j
    float v = (k < IN_DIM) ? W[n * IN_DIM + k] : 0.0f;
    unsigned u = __float_as_uint(v);
    unsigned hi = u & 0xffff0000u;
    float lo = v - __uint_as_float(hi);
    Wh[idx] = (unsigned short)(u >> 16);
    Wl[idx] = (unsigned short)(__float_as_uint(lo) >> 16);
}

// ---------------------------------------------------------------------------
// pre0 = x @ W_ih0^T + b0. One wave per 32 rows; no LDS, no barriers.
// A-fragments loaded directly from global (32B contiguous per lane) and
// converted to hi/lo bf16 in registers; B-fragments are 16B loads from the
// prepacked layout (L2-resident). 3-pass MFMA: Ah*Bh + Al*Bh + Ah*Bl.
// ---------------------------------------------------------------------------
__device__ __forceinline__ void cvt_hilo(const float a[8], bf16x8& hv, bf16x8& lv) {
    union { u32x4 u; bf16x8 v; } H, L;
    #pragma unroll
    for (int p = 0; p < 4; ++p) {
        float a0 = a[2 * p], a1 = a[2 * p + 1];
        unsigned u0 = __float_as_uint(a0), u1 = __float_as_uint(a1);
        unsigned h0 = u0 & 0xffff0000u, h1 = u1 & 0xffff0000u;
        H.u[p] = (u0 >> 16) | h1;
        float l0 = a0 - __uint_as_float(h0);
        float l1 = a1 - __uint_as_float(h1);
        L.u[p] = (__float_as_uint(l0) >> 16) | (__float_as_uint(l1) & 0xffff0000u);
    }
    hv = H.v; lv = L.v;
}

__global__ __launch_bounds__(64) void pre0_gemm(
    const float* __restrict__ X,
    const unsigned short* __restrict__ Wh, const unsigned short* __restrict__ Wl,
    const float* __restrict__ bias, float* __restrict__ out)
{
    const int lane = threadIdx.x;
    const int fr = lane & 15;
    const int kg = lane >> 4;
    const long m0 = (long)blockIdx.x * 32;

    const float* xr0 = X + (m0 + fr) * (long)IN_DIM;
    const float* xr1 = X + (m0 + 16 + fr) * (long)IN_DIM;

    f32x4v acc[2][4];
    #pragma unroll
    for (int mf = 0; mf < 2; ++mf)
        #pragma unroll
        for (int nf = 0; nf < 4; ++nf)
            #pragma unroll
            for (int r = 0; r < 4; ++r) acc[mf][nf][r] = 0.0f;

    for (int kt = 0; kt < KTILES; ++kt) {
        const int kb = kt * 32 + kg * 8;

        // ---- A: 8 fp32 per frag per lane, contiguous 32B (8B-aligned)
        float a0[8], a1[8];
        if (kt < KTILES - 1) {
            #pragma unroll
            for (int q = 0; q < 4; ++q) {
                float2 t0 = *(const float2*)(xr0 + kb + 2 * q);
                float2 t1 = *(const float2*)(xr1 + kb + 2 * q);
                a0[2 * q] = t0.x; a0[2 * q + 1] = t0.y;
                a1[2 * q] = t1.x; a1[2 * q + 1] = t1.y;
            }
        } else {
            #pragma unroll
            for (int j = 0; j < 8; ++j) {
                int k = kb + j;
                a0[j] = (k < IN_DIM) ? xr0[k] : 0.0f;
                a1[j] = (k < IN_DIM) ? xr1[k] : 0.0f;
            }
        }

        // ---- B: prepacked frags, 16B aligned loads (L2-resident)
        const long bbase = (long)(kt * 4 + kg) * 64 * 8;
        bf16x8 bh[4], bl[4];
        #pragma unroll
        for (int nf = 0; nf < 4; ++nf) {
            bh[nf] = *(const bf16x8*)(Wh + bbase + (nf * 16 + fr) * 8);
            bl[nf] = *(const bf16x8*)(Wl + bbase + (nf * 16 + fr) * 8);
        }

        bf16x8 ah0, al0, ah1, al1;
        cvt_hilo(a0, ah0, al0);
        cvt_hilo(a1, ah1, al1);

        #pragma unroll
        for (int nf = 0; nf < 4; ++nf) {
            acc[0][nf] = __builtin_amdgcn_mfma_f32_16x16x32_bf16(ah0, bh[nf], acc[0][nf], 0, 0, 0);
            acc[0][nf] = __builtin_amdgcn_mfma_f32_16x16x32_bf16(al0, bh[nf], acc[0][nf], 0, 0, 0);
            acc[0][nf] = __builtin_amdgcn_mfma_f32_16x16x32_bf16(ah0, bl[nf], acc[0][nf], 0, 0, 0);
            acc[1][nf] = __builtin_amdgcn_mfma_f32_16x16x32_bf16(ah1, bh[nf], acc[1][nf], 0, 0, 0);
            acc[1][nf] = __builtin_amdgcn_mfma_f32_16x16x32_bf16(al1, bh[nf], acc[1][nf], 0, 0, 0);
            acc[1][nf] = __builtin_amdgcn_mfma_f32_16x16x32_bf16(ah1, bl[nf], acc[1][nf], 0, 0, 0);
        }
    }

    // ---- epilogue: +bias, store fp32. C/D map: col=lane&15, row=(lane>>4)*4+r
    float bvv[4];
    #pragma unroll
    for (int nf = 0; nf < 4; ++nf) bvv[nf] = bias[nf * 16 + fr];
    #pragma unroll
    for (int mf = 0; mf < 2; ++mf)
        #pragma unroll
        for (int nf = 0; nf < 4; ++nf)
            #pragma unroll
            for (int r = 0; r < 4; ++r) {
                long row = m0 + mf * 16 + kg * 4 + r;
                out[row * 64 + nf * 16 + fr] = acc[mf][nf][r] + bvv[nf];
            }
}

// ---------------------------------------------------------------------------
// mega_scan: 4-wave layer pipeline (unchanged from R3 — ~45us).
// ---------------------------------------------------------------------------
__global__ __launch_bounds__(256) void mega_scan(
    const float* __restrict__ pre0, const float* __restrict__ whh0,
    const float* __restrict__ wih1, const float* __restrict__ whh1, const float* __restrict__ b1,
    const float* __restrict__ wih2, const float* __restrict__ whh2, const float* __restrict__ b2,
    const float* __restrict__ wih3, const float* __restrict__ whh3, const float* __restrict__ b3,
    const float* __restrict__ w_fc1, const float* __restrict__ b_fc1,
    const float* __restrict__ w_fc2, const float* __restrict__ b_fc2,
    float* __restrict__ out)
{
    __shared__ float buf[3][T_STEPS][16];

    const int b    = blockIdx.x;
    const int tid  = threadIdx.x;
    const int g    = tid & 63;
    const int wv   = tid >> 6;

    bool sel16 = false, sel32 = false;
#if HAVE_PERMLANE_SWAP
    {
        uv2 q16 = __builtin_amdgcn_permlane16_swap((unsigned)g, (unsigned)g, false, false);
        sel16 = (__builtin_amdgcn_readfirstlane((int)q16[1]) == 16);
        uv2 q32 = __builtin_amdgcn_permlane32_swap((unsigned)g, (unsigned)g, false, false);
        sel32 = (__builtin_amdgcn_readfirstlane((int)q32[1]) == 32);
    }
#endif

    const float* wih = nullptr; const float* whh; const float* bias = nullptr;
    if      (wv == 0) { whh = whh0; }
    else if (wv == 1) { wih = wih1; whh = whh1; bias = b1; }
    else if (wv == 2) { wih = wih2; whh = whh2; bias = b2; }
    else              { wih = wih3; whh = whh3; bias = b3; }

    float whh_r[16];
    #pragma unroll
    for (int q = 0; q < 4; ++q)
        *(float4*)&whh_r[q * 4] = *(const float4*)&whh[g * 16 + q * 4];
    float wih_r[16]; float bg = 0.0f;
    if (wv) {
        #pragma unroll
        for (int q = 0; q < 4; ++q)
            *(float4*)&wih_r[q * 4] = *(const float4*)&wih[g * 16 + q * 4];
        bg = bias[g];
    }

    const float* pb = pre0 + (long)b * T_STEPS * 64 + g;
    float pc = 0.0f, p1 = 0.0f, p2 = 0.0f;
    if (wv == 0) { pc = pb[0]; p1 = pb[64]; p2 = pb[128]; }

    float hs[16];
    #pragma unroll
    for (int k = 0; k < 16; ++k) hs[k] = 0.0f;
    float c = 0.0f;

    const int q4 = g >> 4;
    const float escale = (q4 == 2) ? -2.8853900817779268f : -1.4426950408889634f;
    const float am = (q4 == 2) ? 2.0f : 1.0f;
    const float aa = (q4 == 2) ? -1.0f : 0.0f;

    for (int tau = 0; tau < T_STEPS + 3; ++tau) {
        __syncthreads();
        const int t = tau - wv;
        if (t >= 0 && t < T_STEPS) {
            float xr[16];
            if (wv) {
                #pragma unroll
                for (int q = 0; q < 4; ++q)
                    *(float4*)&xr[q * 4] = *(const float4*)&buf[wv - 1][t][q * 4];
            }
            float r0 = fmaf(whh_r[0], hs[0], wv ? bg : pc);
            float r1 = whh_r[1] * hs[1];
            float r2 = whh_r[2] * hs[2];
            float r3 = whh_r[3] * hs[3];
            #pragma unroll
            for (int k = 4; k < 16; k += 4) {
                r0 = fmaf(whh_r[k + 0], hs[k + 0], r0);
                r1 = fmaf(whh_r[k + 1], hs[k + 1], r1);
                r2 = fmaf(whh_r[k + 2], hs[k + 2], r2);
                r3 = fmaf(whh_r[k + 3], hs[k + 3], r3);
            }
            float acc = (r0 + r1) + (r2 + r3);
            if (wv) {
                float p0 = wih_r[0] * xr[0];
                float q1 = wih_r[1] * xr[1];
                float q2 = wih_r[2] * xr[2];
                float q3 = wih_r[3] * xr[3];
                #pragma unroll
                for (int k = 4; k < 16; k += 4) {
                    p0 = fmaf(wih_r[k + 0], xr[k + 0], p0);
                    q1 = fmaf(wih_r[k + 1], xr[k + 1], q1);
                    q2 = fmaf(wih_r[k + 2], xr[k + 2], q2);
                    q3 = fmaf(wih_r[k + 3], xr[k + 3], q3);
                }
                acc += (p0 + q1) + (q2 + q3);
            }
            float e = EXP2F(escale * acc);
            float s = __builtin_amdgcn_rcpf(1.0f + e);
            float a = fmaf(am, s, aa);
#if HAVE_PERMLANE_SWAP
            unsigned au = __float_as_uint(a);
            uv2 r16 = __builtin_amdgcn_permlane16_swap(au, au, false, false);
            uv2 r32 = __builtin_amdgcn_permlane32_swap(au, au, false, false);
            unsigned fvu = sel16 ? r16[1] : r16[0];
            unsigned gvu = sel32 ? r32[1] : r32[0];
            uv2 r48 = __builtin_amdgcn_permlane16_swap(gvu, gvu, false, false);
            unsigned ovu = sel16 ? r48[1] : r48[0];
            float fv = __uint_as_float(fvu);
            float gv = __uint_as_float(gvu);
            float ov = __uint_as_float(ovu);
#else
            float fv = __shfl_xor(a, 16, 64);
            float gv = __shfl_xor(a, 32, 64);
            float ov = __shfl_xor(a, 48, 64);
#endif
            c = fmaf(fv, c, a * gv);
            float e2 = EXP2F(-2.8853900817779268f * c);
            float s2 = __builtin_amdgcn_rcpf(1.0f + e2);
            float hn = fmaf(ov + ov, s2, -ov);
            if (wv < 3 && g < 16) buf[wv][t][g] = hn;
            #pragma unroll
            for (int k = 0; k < 16; ++k) hs[k] = rl_f(hn, k);
            if (wv == 0) {
                pc = p1; p1 = p2;
                int tn = t + 3; tn = tn < T_STEPS ? tn : T_STEPS - 1;
                p2 = pb[(long)tn * 64];
            }
        }
    }

    if (wv == 3 && g < 16) {
        float a1 = b_fc1[g];
        #pragma unroll
        for (int k = 0; k < 16; ++k) a1 = fmaf(w_fc1[g * 16 + k], hs[k], a1);
        a1 = fmaxf(a1, 0.0f);
        float h1[16];
        #pragma unroll
        for (int k = 0; k < 16; ++k) h1[k] = rl_f(a1, k);
        float lg = -3.0e38f;
        if (g < 15) {
            lg = b_fc2[g];
            #pragma unroll
            for (int k = 0; k < 16; ++k) lg = fmaf(w_fc2[g * 16 + k], h1[k], lg);
        }
        float mx = lg;
        #pragma unroll
        for (int d = 8; d >= 1; d >>= 1) mx = fmaxf(mx, __shfl_xor(mx, d, 16));
        float ev = (g < 15) ? EXP2F(1.4426950408889634f * (lg - mx)) : 0.0f;
        float sm = ev;
        #pragma unroll
        for (int d = 8; d >= 1; d >>= 1) sm += __shfl_xor(sm, d, 16);
        if (g < 15) out[b * 15 + g] = ev * __builtin_amdgcn_rcpf(sm);
    }
}

extern "C" void kernel_launch(void* const* d_in, const int* in_sizes, int n_in,
                              void* d_out, int out_size, void* d_ws, size_t ws_size,
                              hipStream_t stream) {
    const float* x    = (const float*)d_in[0];
    const float* wih0 = (const float*)d_in[1];
    const float* whh0 = (const float*)d_in[2];
    const float* b0   = (const float*)d_in[3];
    const float* wih1 = (const float*)d_in[4];
    const float* whh1 = (const float*)d_in[5];
    const float* b1   = (const float*)d_in[6];
    const float* wih2 = (const float*)d_in[7];
    const float* whh2 = (const float*)d_in[8];
    const float* b2   = (const float*)d_in[9];
    const float* wih3 = (const float*)d_in[10];
    const float* whh3 = (const float*)d_in[11];
    const float* b3   = (const float*)d_in[12];
    const float* wfc1 = (const float*)d_in[13];
    const float* bfc1 = (const float*)d_in[14];
    const float* wfc2 = (const float*)d_in[15];
    const float* bfc2 = (const float*)d_in[16];

    // workspace layout
    float* pre0 = (float*)d_ws;                              // 13,107,200 B
    unsigned short* Wh = (unsigned short*)((char*)d_ws + 13107200);   // 139,264 B
    unsigned short* Wl = (unsigned short*)((char*)d_ws + 13107200 + 139264);

    prepack_w<<<dim3((KTILES * 4 * 64 * 8 + 255) / 256), dim3(256), 0, stream>>>(wih0, Wh, Wl);
    pre0_gemm<<<dim3(M_TOTAL / 32), dim3(64), 0, stream>>>(x, Wh, Wl, b0, pre0);
    mega_scan<<<dim3(256), dim3(256), 0, stream>>>(pre0, whh0,
        wih1, whh1, b1, wih2, whh2, b2, wih3, whh3, b3,
        wfc1, bfc1, wfc2, bfc2, (float*)d_out);
}